// Round 2
// baseline (548.924 us; speedup 1.0000x reference)
//
#include <hip/hip_runtime.h>

#define NN 50000
#define NE 800000
#define DIN 256
#define DH 128

typedef float f32x4 __attribute__((ext_vector_type(4)));
typedef __bf16 bf16x8 __attribute__((ext_vector_type(8)));
typedef unsigned short u16;
typedef unsigned int u32;

__device__ __forceinline__ u16 f2b(float f) { return __builtin_bit_cast(u16, (__bf16)f); }
__device__ __forceinline__ float lo_f(u32 u) { return (float)__builtin_bit_cast(__bf16, (u16)(u & 0xFFFFu)); }
__device__ __forceinline__ float hi_f(u32 u) { return (float)__builtin_bit_cast(__bf16, (u16)(u >> 16)); }

__device__ __forceinline__ f32x4 mfma16(bf16x8 a, bf16x8 b, f32x4 c) {
    return __builtin_amdgcn_mfma_f32_16x16x32_bf16(a, b, c, 0, 0, 0);
}

// ---------------- weight pre-swizzle (fp32 -> bf16 B-fragment order) ----------------
// frag layout: lane l holds B[k = kt*32 + (l>>4)*8 + j][n = nt*16 + (l&15)], j=0..7
// dst[( (kt*8+nt)*64 + lane )*8 + j]
__global__ void k_prep_w(const float* __restrict__ w1, const float* __restrict__ w2,
                         const float* __restrict__ wg,
                         u16* __restrict__ w12f, u16* __restrict__ wgf) {
    int t = blockIdx.x * 256 + threadIdx.x;  // 0..8191
    const float* src; u16* dst; int id;
    if (t < 2048)      { src = w1; dst = w12f;          id = t; }
    else if (t < 4096) { src = w2; dst = w12f + 16384;  id = t - 2048; }
    else               { src = wg; dst = wgf;           id = t - 4096; }
    int lane = id & 63, frag = id >> 6;
    int kt = frag >> 3, nt = frag & 7;
    int k0 = kt * 32 + (lane >> 4) * 8, n = nt * 16 + (lane & 15);
    u16 v[8];
#pragma unroll
    for (int j = 0; j < 8; ++j) v[j] = f2b(src[(k0 + j) * 128 + n]);
#pragma unroll
    for (int j = 0; j < 8; ++j) dst[id * 8 + j] = v[j];
}

// ---------------- degree histogram ----------------
__global__ void k_hist(const int* __restrict__ dst, int* __restrict__ cnt) {
    int e = blockIdx.x * 256 + threadIdx.x;  // grid covers exactly NE
    atomicAdd(&cnt[dst[e]], 1);
}

__global__ void k_dinv(const int* __restrict__ cnt, float* __restrict__ dinv) {
    int i = blockIdx.x * 256 + threadIdx.x;
    if (i < NN) dinv[i] = rsqrtf((float)cnt[i] + 1.0f);  // +1 self loop
}

// ---------------- exclusive scan (single block, 1024 threads) ----------------
__global__ void k_scan(const int* __restrict__ cnt, int* __restrict__ rowptr,
                       int* __restrict__ cursor) {
    __shared__ int part[1024];
    int t = threadIdx.x;
    const int CH = (NN + 1023) / 1024;  // 49
    int lo = t * CH, hi = lo + CH; if (hi > NN) hi = NN; if (lo > NN) lo = NN;
    int s = 0;
    for (int i = lo; i < hi; ++i) s += cnt[i];
    part[t] = s;
    __syncthreads();
    for (int off = 1; off < 1024; off <<= 1) {
        int v = part[t];
        int add = (t >= off) ? part[t - off] : 0;
        __syncthreads();
        part[t] = v + add;
        __syncthreads();
    }
    int run = (t == 0) ? 0 : part[t - 1];
    for (int i = lo; i < hi; ++i) { rowptr[i] = run; cursor[i] = run; run += cnt[i]; }
    if (t == 1023) rowptr[NN] = run;
}

__global__ void k_fill(const int* __restrict__ src, const int* __restrict__ dst,
                       int* __restrict__ cursor, int* __restrict__ csr) {
    int e = blockIdx.x * 256 + threadIdx.x;
    int p = atomicAdd(&cursor[dst[e]], 1);
    csr[p] = src[e];
}

// ---------------- h0 = x @ W_gcn  (fp32 x -> bf16 MFMA) ----------------
__global__ __launch_bounds__(512) void k_gemm_x(const float* __restrict__ x,
                                                const u16* __restrict__ wgf,
                                                u16* __restrict__ h0) {
    int wave = threadIdx.x >> 6, lane = threadIdx.x & 63;
    int l15 = lane & 15, q = lane >> 4;
    int rowBase = blockIdx.x * 256 + wave * 32;

    bf16x8 a[2][8];
#pragma unroll
    for (int mi = 0; mi < 2; ++mi) {
        int r = rowBase + mi * 16 + l15; if (r >= NN) r = NN - 1;
        const float* rp = x + (size_t)r * DIN + q * 8;
#pragma unroll
        for (int kt = 0; kt < 8; ++kt) {
            f32x4 f0 = *(const f32x4*)(rp + kt * 32);
            f32x4 f1 = *(const f32x4*)(rp + kt * 32 + 4);
            bf16x8 aa;
#pragma unroll
            for (int j = 0; j < 4; ++j) { aa[j] = (__bf16)f0[j]; aa[j + 4] = (__bf16)f1[j]; }
            a[mi][kt] = aa;
        }
    }
    f32x4 z = {0.f, 0.f, 0.f, 0.f};
    f32x4 acc[2][8];
#pragma unroll
    for (int mi = 0; mi < 2; ++mi)
#pragma unroll
        for (int nt = 0; nt < 8; ++nt) acc[mi][nt] = z;

#pragma unroll
    for (int kt = 0; kt < 8; ++kt)
#pragma unroll
        for (int nt = 0; nt < 8; ++nt) {
            bf16x8 b = *(const bf16x8*)(wgf + ((kt * 8 + nt) * 64 + lane) * 8);
            acc[0][nt] = mfma16(a[0][kt], b, acc[0][nt]);
            acc[1][nt] = mfma16(a[1][kt], b, acc[1][nt]);
        }
#pragma unroll
    for (int mi = 0; mi < 2; ++mi)
#pragma unroll
        for (int nt = 0; nt < 8; ++nt)
#pragma unroll
            for (int rg = 0; rg < 4; ++rg) {
                int r = rowBase + mi * 16 + q * 4 + rg;
                if (r < NN) h0[r * DH + nt * 16 + l15] = f2b(acc[mi][nt][rg]);
            }
}

// ---------------- GCN aggregate: one wave per node, CSR gather-reduce ----------------
__global__ __launch_bounds__(256) void k_aggregate(const u16* __restrict__ h0,
                                                   const float* __restrict__ dinv,
                                                   const int* __restrict__ rowptr,
                                                   const int* __restrict__ csr,
                                                   const float* __restrict__ bg,
                                                   u16* __restrict__ hA) {
    int v = blockIdx.x * 4 + (threadIdx.x >> 6);
    int lane = threadIdx.x & 63;
    const u32* h0u = (const u32*)h0;
    u32 su = h0u[v * 64 + lane];
    float dv = dinv[v];
    float a0 = 0.f, a1 = 0.f;
    int beg = rowptr[v], end = rowptr[v + 1];
    for (int j = beg; j < end; ++j) {
        int s = csr[j];
        float ds = dinv[s];
        u32 u = h0u[s * 64 + lane];
        a0 += ds * lo_f(u);
        a1 += ds * hi_f(u);
    }
    float bg0 = bg[2 * lane], bg1 = bg[2 * lane + 1];
    a0 = a0 * dv + dv * dv * lo_f(su) + bg0;
    a1 = a1 * dv + dv * dv * hi_f(su) + bg1;
    a0 = a0 > 0.f ? a0 : 0.f;
    a1 = a1 > 0.f ? a1 : 0.f;
    ((u32*)hA)[v * 64 + lane] = (u32)f2b(a0) | ((u32)f2b(a1) << 16);
}

// ---------------- fused node MLP: h2 = relu(relu(hA@W1+b1)@W2+b2) ----------------
__global__ __launch_bounds__(512) void k_node_mlp(const u16* __restrict__ hA,
                                                  const u16* __restrict__ wf,
                                                  const float* __restrict__ b1,
                                                  const float* __restrict__ b2,
                                                  u16* __restrict__ h2) {
    __shared__ __align__(16) u16 wlds[32768];          // w1(16384) || w2(16384)
    __shared__ __align__(16) u16 scratch[8][16 * 136]; // per-wave transpose tile
    {
        const uint4* s = (const uint4*)wf;
        uint4* d = (uint4*)wlds;
        for (int i = threadIdx.x; i < 4096; i += 512) d[i] = s[i];
    }
    __syncthreads();
    int wave = threadIdx.x >> 6, lane = threadIdx.x & 63;
    int l15 = lane & 15, q = lane >> 4;
    int rowBase = blockIdx.x * 256 + wave * 32;
    u16* sw = scratch[wave];

    bf16x8 a[2][4];
#pragma unroll
    for (int mi = 0; mi < 2; ++mi) {
        int r = rowBase + mi * 16 + l15; if (r >= NN) r = NN - 1;
        const u16* rp = hA + r * DH + q * 8;
#pragma unroll
        for (int kt = 0; kt < 4; ++kt) a[mi][kt] = *(const bf16x8*)(rp + kt * 32);
    }
    f32x4 z = {0.f, 0.f, 0.f, 0.f};
    f32x4 acc1[2][8];
#pragma unroll
    for (int mi = 0; mi < 2; ++mi)
#pragma unroll
        for (int nt = 0; nt < 8; ++nt) acc1[mi][nt] = z;
#pragma unroll
    for (int kt = 0; kt < 4; ++kt)
#pragma unroll
        for (int nt = 0; nt < 8; ++nt) {
            bf16x8 b = *(const bf16x8*)(wlds + (kt * 8 + nt) * 512 + lane * 8);
            acc1[0][nt] = mfma16(a[0][kt], b, acc1[0][nt]);
            acc1[1][nt] = mfma16(a[1][kt], b, acc1[1][nt]);
        }
    float bb1[8], bb2[8];
#pragma unroll
    for (int nt = 0; nt < 8; ++nt) { bb1[nt] = b1[nt * 16 + l15]; bb2[nt] = b2[nt * 16 + l15]; }

    bf16x8 a2[2][4];
#pragma unroll
    for (int mi = 0; mi < 2; ++mi) {
#pragma unroll
        for (int nt = 0; nt < 8; ++nt)
#pragma unroll
            for (int rg = 0; rg < 4; ++rg) {
                float v = acc1[mi][nt][rg] + bb1[nt];
                v = v > 0.f ? v : 0.f;
                sw[(q * 4 + rg) * 136 + nt * 16 + l15] = f2b(v);
            }
#pragma unroll
        for (int kt = 0; kt < 4; ++kt)
            a2[mi][kt] = *(const bf16x8*)(sw + l15 * 136 + kt * 32 + q * 8);
    }
    f32x4 acc2[2][8];
#pragma unroll
    for (int mi = 0; mi < 2; ++mi)
#pragma unroll
        for (int nt = 0; nt < 8; ++nt) acc2[mi][nt] = z;
#pragma unroll
    for (int kt = 0; kt < 4; ++kt)
#pragma unroll
        for (int nt = 0; nt < 8; ++nt) {
            bf16x8 b = *(const bf16x8*)(wlds + 16384 + (kt * 8 + nt) * 512 + lane * 8);
            acc2[0][nt] = mfma16(a2[0][kt], b, acc2[0][nt]);
            acc2[1][nt] = mfma16(a2[1][kt], b, acc2[1][nt]);
        }
#pragma unroll
    for (int mi = 0; mi < 2; ++mi)
#pragma unroll
        for (int nt = 0; nt < 8; ++nt)
#pragma unroll
            for (int rg = 0; rg < 4; ++rg) {
                int r = rowBase + mi * 16 + q * 4 + rg;
                if (r < NN) {
                    float v = acc2[mi][nt][rg] + bb2[nt];
                    v = v > 0.f ? v : 0.f;
                    h2[r * DH + nt * 16 + l15] = f2b(v);
                }
            }
}

// ---------------- fused edge MLP + out layer + log_softmax (fp32 out) ----------------
__global__ __launch_bounds__(512) void k_edge_mlp(const u16* __restrict__ h2,
                                                  const int* __restrict__ ei,
                                                  const u16* __restrict__ wf,
                                                  const float* __restrict__ b1,
                                                  const float* __restrict__ b2,
                                                  const float* __restrict__ ow,
                                                  const float* __restrict__ ob,
                                                  float2* __restrict__ outp) {
    __shared__ __align__(16) u16 wlds[32768];
    __shared__ __align__(16) u16 scratch[8][16 * 136];
    {
        const uint4* s = (const uint4*)wf;
        uint4* d = (uint4*)wlds;
        for (int i = threadIdx.x; i < 4096; i += 512) d[i] = s[i];
    }
    __syncthreads();
    int wave = threadIdx.x >> 6, lane = threadIdx.x & 63;
    int l15 = lane & 15, q = lane >> 4;
    int eBase = blockIdx.x * 256 + wave * 32;
    const int* ei0 = ei;
    const int* ei1 = ei + NE;
    u16* sw = scratch[wave];

    // gather A = h2[src] + h2[dst]  (0.5 folded into GEMM1 epilogue)
    bf16x8 a[2][4];
#pragma unroll
    for (int mi = 0; mi < 2; ++mi) {
        int e = eBase + mi * 16 + l15;
        int s = ei0[e], d = ei1[e];
        const u16* ps = h2 + s * DH + q * 8;
        const u16* pd = h2 + d * DH + q * 8;
#pragma unroll
        for (int kt = 0; kt < 4; ++kt) {
            bf16x8 hs = *(const bf16x8*)(ps + kt * 32);
            bf16x8 hd = *(const bf16x8*)(pd + kt * 32);
            bf16x8 r;
#pragma unroll
            for (int j = 0; j < 8; ++j) r[j] = (__bf16)((float)hs[j] + (float)hd[j]);
            a[mi][kt] = r;
        }
    }
    f32x4 z = {0.f, 0.f, 0.f, 0.f};
    f32x4 acc1[2][8];
#pragma unroll
    for (int mi = 0; mi < 2; ++mi)
#pragma unroll
        for (int nt = 0; nt < 8; ++nt) acc1[mi][nt] = z;
#pragma unroll
    for (int kt = 0; kt < 4; ++kt)
#pragma unroll
        for (int nt = 0; nt < 8; ++nt) {
            bf16x8 b = *(const bf16x8*)(wlds + (kt * 8 + nt) * 512 + lane * 8);
            acc1[0][nt] = mfma16(a[0][kt], b, acc1[0][nt]);
            acc1[1][nt] = mfma16(a[1][kt], b, acc1[1][nt]);
        }
    float bb1[8], bb2[8];
#pragma unroll
    for (int nt = 0; nt < 8; ++nt) { bb1[nt] = b1[nt * 16 + l15]; bb2[nt] = b2[nt * 16 + l15]; }

    bf16x8 a2[2][4];
#pragma unroll
    for (int mi = 0; mi < 2; ++mi) {
#pragma unroll
        for (int nt = 0; nt < 8; ++nt)
#pragma unroll
            for (int rg = 0; rg < 4; ++rg) {
                float v = acc1[mi][nt][rg] * 0.5f + bb1[nt];
                v = v > 0.f ? v : 0.f;
                sw[(q * 4 + rg) * 136 + nt * 16 + l15] = f2b(v);
            }
#pragma unroll
        for (int kt = 0; kt < 4; ++kt)
            a2[mi][kt] = *(const bf16x8*)(sw + l15 * 136 + kt * 32 + q * 8);
    }
    f32x4 acc2[2][8];
#pragma unroll
    for (int mi = 0; mi < 2; ++mi)
#pragma unroll
        for (int nt = 0; nt < 8; ++nt) acc2[mi][nt] = z;
#pragma unroll
    for (int kt = 0; kt < 4; ++kt)
#pragma unroll
        for (int nt = 0; nt < 8; ++nt) {
            bf16x8 b = *(const bf16x8*)(wlds + 16384 + (kt * 8 + nt) * 512 + lane * 8);
            acc2[0][nt] = mfma16(a2[0][kt], b, acc2[0][nt]);
            acc2[1][nt] = mfma16(a2[1][kt], b, acc2[1][nt]);
        }
    // out layer: per-lane partial over its 8 cols, shfl-xor reduce across the 16-lane group
    float owp0[8], owp1[8];
#pragma unroll
    for (int nt = 0; nt < 8; ++nt) {
        int k = nt * 16 + l15;
        owp0[nt] = ow[2 * k];
        owp1[nt] = ow[2 * k + 1];
    }
    float ob0 = ob[0], ob1 = ob[1];
#pragma unroll
    for (int mi = 0; mi < 2; ++mi)
#pragma unroll
        for (int rg = 0; rg < 4; ++rg) {
            float p0 = 0.f, p1 = 0.f;
#pragma unroll
            for (int nt = 0; nt < 8; ++nt) {
                float t = acc2[mi][nt][rg] + bb2[nt];
                t = t > 0.f ? t : 0.f;
                p0 += t * owp0[nt];
                p1 += t * owp1[nt];
            }
#pragma unroll
            for (int m = 1; m < 16; m <<= 1) {
                p0 += __shfl_xor(p0, m, 64);
                p1 += __shfl_xor(p1, m, 64);
            }
            if (l15 == 0) {
                int e = eBase + mi * 16 + q * 4 + rg;
                float s0 = p0 + ob0, s1 = p1 + ob1;
                float mx = fmaxf(s0, s1);
                float lse = mx + __logf(__expf(s0 - mx) + __expf(s1 - mx));
                outp[e] = make_float2(s0 - lse, s1 - lse);
            }
        }
}

extern "C" void kernel_launch(void* const* d_in, const int* in_sizes, int n_in,
                              void* d_out, int out_size, void* d_ws, size_t ws_size,
                              hipStream_t stream) {
    const float* x  = (const float*)d_in[0];
    const int* ei   = (const int*)d_in[1];
    const float* wg = (const float*)d_in[2];
    const float* bg = (const float*)d_in[3];
    const float* w1 = (const float*)d_in[4];
    const float* b1 = (const float*)d_in[5];
    const float* w2 = (const float*)d_in[6];
    const float* b2 = (const float*)d_in[7];
    const float* ow = (const float*)d_in[8];
    const float* ob = (const float*)d_in[9];
    float2* out = (float2*)d_out;

    char* ws = (char*)d_ws;
    size_t off = 0;
    auto alloc = [&](size_t bytes) { void* p = ws + off; off += (bytes + 255) & ~(size_t)255; return p; };
    u16* h0      = (u16*)alloc((size_t)NN * DH * 2);   // also reused as h2
    u16* hA      = (u16*)alloc((size_t)NN * DH * 2);
    int* csr     = (int*)alloc((size_t)NE * 4);
    int* cnt     = (int*)alloc((size_t)NN * 4);
    int* cursor  = (int*)alloc((size_t)NN * 4);
    int* rowptr  = (int*)alloc((size_t)(NN + 1) * 4);
    float* dinv  = (float*)alloc((size_t)NN * 4);
    u16* w12f    = (u16*)alloc(65536);
    u16* wgf     = (u16*)alloc(65536);
    u16* h2      = h0;  // alias: h0 dead after aggregation

    hipMemsetAsync(cnt, 0, (size_t)NN * 4, stream);
    k_prep_w<<<32, 256, 0, stream>>>(w1, w2, wg, w12f, wgf);
    k_hist<<<NE / 256, 256, 0, stream>>>(ei + NE, cnt);
    k_dinv<<<(NN + 255) / 256, 256, 0, stream>>>(cnt, dinv);
    k_scan<<<1, 1024, 0, stream>>>(cnt, rowptr, cursor);
    k_fill<<<NE / 256, 256, 0, stream>>>(ei, ei + NE, cursor, csr);
    k_gemm_x<<<(NN + 255) / 256, 512, 0, stream>>>(x, wgf, h0);
    k_aggregate<<<NN / 4, 256, 0, stream>>>(h0, dinv, rowptr, csr, bg, hA);
    k_node_mlp<<<(NN + 255) / 256, 512, 0, stream>>>(hA, w12f, b1, b2, h2);
    k_edge_mlp<<<NE / 256, 512, 0, stream>>>(h2, ei, w12f, b1, b2, ow, ob, out);
}

// Round 3
// 419.524 us; speedup vs baseline: 1.3084x; 1.3084x over previous
//
#include <hip/hip_runtime.h>

#define NN 50000
#define NE 800000
#define DIN 256
#define DH 128

typedef float f32x4 __attribute__((ext_vector_type(4)));
typedef __bf16 bf16x8 __attribute__((ext_vector_type(8)));
typedef unsigned short u16;
typedef unsigned int u32;

__device__ __forceinline__ u16 f2b(float f) { return __builtin_bit_cast(u16, (__bf16)f); }
__device__ __forceinline__ float lo_f(u32 u) { return (float)__builtin_bit_cast(__bf16, (u16)(u & 0xFFFFu)); }
__device__ __forceinline__ float hi_f(u32 u) { return (float)__builtin_bit_cast(__bf16, (u16)(u >> 16)); }

__device__ __forceinline__ f32x4 mfma16(bf16x8 a, bf16x8 b, f32x4 c) {
    return __builtin_amdgcn_mfma_f32_16x16x32_bf16(a, b, c, 0, 0, 0);
}

// ---------------- weight pre-swizzle (fp32 -> bf16 B-fragment order) ----------------
// lane l holds B[k = kt*32 + (l>>4)*8 + j][n = nt*16 + (l&15)], j=0..7
// dst[( (kt*8+nt)*64 + lane )*8 + j]
__global__ void k_prep_w(const float* __restrict__ w1, const float* __restrict__ w2,
                         const float* __restrict__ wg,
                         u16* __restrict__ w12f, u16* __restrict__ wgf) {
    int t = blockIdx.x * 256 + threadIdx.x;  // 0..8191
    const float* src; u16* dst; int id;
    if (t < 2048)      { src = w1; dst = w12f;          id = t; }
    else if (t < 4096) { src = w2; dst = w12f + 16384;  id = t - 2048; }
    else               { src = wg; dst = wgf;           id = t - 4096; }
    int lane = id & 63, frag = id >> 6;
    int kt = frag >> 3, nt = frag & 7;
    int k0 = kt * 32 + (lane >> 4) * 8, n = nt * 16 + (lane & 15);
    u16 v[8];
#pragma unroll
    for (int j = 0; j < 8; ++j) v[j] = f2b(src[(k0 + j) * 128 + n]);
#pragma unroll
    for (int j = 0; j < 8; ++j) dst[id * 8 + j] = v[j];
}

// ---------------- degree histogram ----------------
__global__ void k_hist(const int* __restrict__ dst, int* __restrict__ cnt) {
    int e = blockIdx.x * 256 + threadIdx.x;
    atomicAdd(&cnt[dst[e]], 1);
}

// ---------------- exclusive scan + dinv (single block, 1024 threads) ----------------
__global__ void k_scan(const int* __restrict__ cnt, int* __restrict__ rowptr,
                       int* __restrict__ cursor, float* __restrict__ dinv) {
    __shared__ int part[1024];
    int t = threadIdx.x;
    const int CH = (NN + 1023) / 1024;  // 49
    int lo = t * CH, hi = lo + CH; if (hi > NN) hi = NN; if (lo > NN) lo = NN;
    int s = 0;
#pragma unroll 7
    for (int i = lo; i < hi; ++i) {
        int c = cnt[i];
        s += c;
        dinv[i] = rsqrtf((float)c + 1.0f);  // +1 self loop
    }
    part[t] = s;
    __syncthreads();
    for (int off = 1; off < 1024; off <<= 1) {
        int v = part[t];
        int add = (t >= off) ? part[t - off] : 0;
        __syncthreads();
        part[t] = v + add;
        __syncthreads();
    }
    int run = (t == 0) ? 0 : part[t - 1];
#pragma unroll 7
    for (int i = lo; i < hi; ++i) { rowptr[i] = run; cursor[i] = run; run += cnt[i]; }
    if (t == 1023) rowptr[NN] = run;
}

__global__ void k_fill(const int* __restrict__ src, const int* __restrict__ dst,
                       int* __restrict__ cursor, int* __restrict__ csr) {
    int e = blockIdx.x * 256 + threadIdx.x;
    int p = atomicAdd(&cursor[dst[e]], 1);
    csr[p] = src[e];
}

// ---------------- h0pre = (x @ W_gcn) * dinv[row]  (fp32 x -> bf16 MFMA) ----------------
__global__ __launch_bounds__(256) void k_gemm_x(const float* __restrict__ x,
                                                const u16* __restrict__ wgf,
                                                const float* __restrict__ dinv,
                                                u16* __restrict__ h0pre) {
    int wave = threadIdx.x >> 6, lane = threadIdx.x & 63;
    int l15 = lane & 15, q = lane >> 4;
    int rowBase = blockIdx.x * 128 + wave * 32;

    bf16x8 a[2][8];
#pragma unroll
    for (int mi = 0; mi < 2; ++mi) {
        int r = rowBase + mi * 16 + l15; if (r >= NN) r = NN - 1;
        const float* rp = x + (size_t)r * DIN + q * 8;
#pragma unroll
        for (int kt = 0; kt < 8; ++kt) {
            f32x4 f0 = *(const f32x4*)(rp + kt * 32);
            f32x4 f1 = *(const f32x4*)(rp + kt * 32 + 4);
            bf16x8 aa;
#pragma unroll
            for (int j = 0; j < 4; ++j) { aa[j] = (__bf16)f0[j]; aa[j + 4] = (__bf16)f1[j]; }
            a[mi][kt] = aa;
        }
    }
    f32x4 z = {0.f, 0.f, 0.f, 0.f};
    f32x4 acc[2][8];
#pragma unroll
    for (int mi = 0; mi < 2; ++mi)
#pragma unroll
        for (int nt = 0; nt < 8; ++nt) acc[mi][nt] = z;

#pragma unroll
    for (int kt = 0; kt < 8; ++kt)
#pragma unroll
        for (int nt = 0; nt < 8; ++nt) {
            bf16x8 b = *(const bf16x8*)(wgf + ((kt * 8 + nt) * 64 + lane) * 8);
            acc[0][nt] = mfma16(a[0][kt], b, acc[0][nt]);
            acc[1][nt] = mfma16(a[1][kt], b, acc[1][nt]);
        }
#pragma unroll
    for (int mi = 0; mi < 2; ++mi)
#pragma unroll
        for (int rg = 0; rg < 4; ++rg) {
            int r = rowBase + mi * 16 + q * 4 + rg;
            if (r < NN) {
                float dv = dinv[r];
#pragma unroll
                for (int nt = 0; nt < 8; ++nt)
                    h0pre[r * DH + nt * 16 + l15] = f2b(acc[mi][nt][rg] * dv);
            }
        }
}

// ---------------- GCN aggregate: hA[v] = relu(dinv[v] * (sum_{s in N(v)} h0pre[s] + h0pre[v]) + bg) ----------------
__global__ __launch_bounds__(256) void k_aggregate(const u16* __restrict__ h0pre,
                                                   const float* __restrict__ dinv,
                                                   const int* __restrict__ rowptr,
                                                   const int* __restrict__ csr,
                                                   const float* __restrict__ bg,
                                                   u16* __restrict__ hA) {
    int v = blockIdx.x * 4 + (threadIdx.x >> 6);
    int lane = threadIdx.x & 63;
    const u32* h = (const u32*)h0pre;
    u32 su = h[v * 64 + lane];
    float a0 = lo_f(su), a1 = hi_f(su);  // self-loop (scale folded: dv^2*h = dv*h0pre)
    float b0 = 0.f, b1 = 0.f, c0 = 0.f, c1 = 0.f, d0 = 0.f, d1 = 0.f;
    int beg = rowptr[v], end = rowptr[v + 1];
    int j = beg;
    for (; j + 4 <= end; j += 4) {
        int s0 = csr[j], s1 = csr[j + 1], s2 = csr[j + 2], s3 = csr[j + 3];
        u32 u0 = h[s0 * 64 + lane];
        u32 u1 = h[s1 * 64 + lane];
        u32 u2 = h[s2 * 64 + lane];
        u32 u3 = h[s3 * 64 + lane];
        a0 += lo_f(u0); a1 += hi_f(u0);
        b0 += lo_f(u1); b1 += hi_f(u1);
        c0 += lo_f(u2); c1 += hi_f(u2);
        d0 += lo_f(u3); d1 += hi_f(u3);
    }
    for (; j < end; ++j) {
        int s = csr[j];
        u32 u = h[s * 64 + lane];
        a0 += lo_f(u); a1 += hi_f(u);
    }
    a0 += b0 + c0 + d0; a1 += b1 + c1 + d1;
    float dv = dinv[v];
    float bg0 = bg[2 * lane], bg1 = bg[2 * lane + 1];
    a0 = fmaxf(a0 * dv + bg0, 0.f);
    a1 = fmaxf(a1 * dv + bg1, 0.f);
    ((u32*)hA)[v * 64 + lane] = (u32)f2b(a0) | ((u32)f2b(a1) << 16);
}

// ---------------- fused node MLP (LDS overlay: W1 -> scratch -> W2 in one 32KB buffer) ----------------
__global__ __launch_bounds__(256) void k_node_mlp(const u16* __restrict__ hA,
                                                  const u16* __restrict__ wf,
                                                  const float* __restrict__ b1,
                                                  const float* __restrict__ b2,
                                                  u16* __restrict__ h2) {
    __shared__ __align__(16) u16 wlds[16384];  // 32 KB: W1, then per-wave scratch, then W2
    {
        const uint4* s = (const uint4*)wf;
        uint4* d = (uint4*)wlds;
        for (int i = threadIdx.x; i < 2048; i += 256) d[i] = s[i];
    }
    __syncthreads();
    int wave = threadIdx.x >> 6, lane = threadIdx.x & 63;
    int l15 = lane & 15, q = lane >> 4;
    int rowBase = blockIdx.x * 128 + wave * 32;
    u16* sw = wlds + wave * 2176;  // 16 x 136 u16 per wave

    bf16x8 a[2][4];
#pragma unroll
    for (int mi = 0; mi < 2; ++mi) {
        int r = rowBase + mi * 16 + l15; if (r >= NN) r = NN - 1;
        const u16* rp = hA + r * DH + q * 8;
#pragma unroll
        for (int kt = 0; kt < 4; ++kt) a[mi][kt] = *(const bf16x8*)(rp + kt * 32);
    }
    f32x4 z = {0.f, 0.f, 0.f, 0.f};
    f32x4 acc1[2][8];
#pragma unroll
    for (int mi = 0; mi < 2; ++mi)
#pragma unroll
        for (int nt = 0; nt < 8; ++nt) acc1[mi][nt] = z;
#pragma unroll
    for (int kt = 0; kt < 4; ++kt)
#pragma unroll
        for (int nt = 0; nt < 8; ++nt) {
            bf16x8 b = *(const bf16x8*)(wlds + (kt * 8 + nt) * 512 + lane * 8);
            acc1[0][nt] = mfma16(a[0][kt], b, acc1[0][nt]);
            acc1[1][nt] = mfma16(a[1][kt], b, acc1[1][nt]);
        }
    float bb1[8], bb2[8];
#pragma unroll
    for (int nt = 0; nt < 8; ++nt) { bb1[nt] = b1[nt * 16 + l15]; bb2[nt] = b2[nt * 16 + l15]; }

    __syncthreads();  // everyone done reading W1 before scratch overlays it
    bf16x8 a2[2][4];
#pragma unroll
    for (int mi = 0; mi < 2; ++mi) {
#pragma unroll
        for (int nt = 0; nt < 8; ++nt)
#pragma unroll
            for (int rg = 0; rg < 4; ++rg) {
                float v = acc1[mi][nt][rg] + bb1[nt];
                v = v > 0.f ? v : 0.f;
                sw[(q * 4 + rg) * 136 + nt * 16 + l15] = f2b(v);
            }
#pragma unroll
        for (int kt = 0; kt < 4; ++kt)
            a2[mi][kt] = *(const bf16x8*)(sw + l15 * 136 + kt * 32 + q * 8);
    }
    __syncthreads();  // everyone done with scratch before W2 overlays it
    {
        const uint4* s = (const uint4*)(wf + 16384);
        uint4* d = (uint4*)wlds;
        for (int i = threadIdx.x; i < 2048; i += 256) d[i] = s[i];
    }
    __syncthreads();
    f32x4 acc2[2][8];
#pragma unroll
    for (int mi = 0; mi < 2; ++mi)
#pragma unroll
        for (int nt = 0; nt < 8; ++nt) acc2[mi][nt] = z;
#pragma unroll
    for (int kt = 0; kt < 4; ++kt)
#pragma unroll
        for (int nt = 0; nt < 8; ++nt) {
            bf16x8 b = *(const bf16x8*)(wlds + (kt * 8 + nt) * 512 + lane * 8);
            acc2[0][nt] = mfma16(a2[0][kt], b, acc2[0][nt]);
            acc2[1][nt] = mfma16(a2[1][kt], b, acc2[1][nt]);
        }
#pragma unroll
    for (int mi = 0; mi < 2; ++mi)
#pragma unroll
        for (int nt = 0; nt < 8; ++nt)
#pragma unroll
            for (int rg = 0; rg < 4; ++rg) {
                int r = rowBase + mi * 16 + q * 4 + rg;
                if (r < NN) {
                    float v = acc2[mi][nt][rg] + bb2[nt];
                    v = v > 0.f ? v : 0.f;
                    h2[r * DH + nt * 16 + l15] = f2b(v);
                }
            }
}

// ---------------- fused edge MLP: direct-feed gather GEMM + out layer + log_softmax ----------------
__global__ __launch_bounds__(256) void k_edge_mlp(const u16* __restrict__ h2,
                                                  const int* __restrict__ ei,
                                                  const u16* __restrict__ wf,
                                                  const float* __restrict__ b1,
                                                  const float* __restrict__ b2,
                                                  const float* __restrict__ ow,
                                                  const float* __restrict__ ob,
                                                  float2* __restrict__ outp) {
    __shared__ __align__(16) u16 wlds[16384];  // 32 KB overlay buffer
    {
        const uint4* s = (const uint4*)wf;
        uint4* d = (uint4*)wlds;
        for (int i = threadIdx.x; i < 2048; i += 256) d[i] = s[i];
    }
    __syncthreads();
    int wave = threadIdx.x >> 6, lane = threadIdx.x & 63;
    int l15 = lane & 15, q = lane >> 4;
    int eBase = blockIdx.x * 128 + wave * 32;
    u16* sw = wlds + wave * 2176;

    int e0 = eBase + l15, e1 = eBase + 16 + l15;
    const u16* ps0 = h2 + ei[e0] * DH + q * 8;
    const u16* pd0 = h2 + ei[NE + e0] * DH + q * 8;
    const u16* ps1 = h2 + ei[e1] * DH + q * 8;
    const u16* pd1 = h2 + ei[NE + e1] * DH + q * 8;

    f32x4 z = {0.f, 0.f, 0.f, 0.f};
    f32x4 acc1[2][8];
#pragma unroll
    for (int mi = 0; mi < 2; ++mi)
#pragma unroll
        for (int nt = 0; nt < 8; ++nt) acc1[mi][nt] = z;

    // GEMM1: acc1 = hs@W1 + hd@W1  (sum in accumulator; 0.5 applied in epilogue)
#pragma unroll
    for (int kt = 0; kt < 4; ++kt) {
        bf16x8 as0 = *(const bf16x8*)(ps0 + kt * 32);
        bf16x8 ad0 = *(const bf16x8*)(pd0 + kt * 32);
        bf16x8 as1 = *(const bf16x8*)(ps1 + kt * 32);
        bf16x8 ad1 = *(const bf16x8*)(pd1 + kt * 32);
#pragma unroll
        for (int nt = 0; nt < 8; ++nt) {
            bf16x8 b = *(const bf16x8*)(wlds + (kt * 8 + nt) * 512 + lane * 8);
            acc1[0][nt] = mfma16(as0, b, acc1[0][nt]);
            acc1[0][nt] = mfma16(ad0, b, acc1[0][nt]);
            acc1[1][nt] = mfma16(as1, b, acc1[1][nt]);
            acc1[1][nt] = mfma16(ad1, b, acc1[1][nt]);
        }
    }
    float bb1[8], bb2[8];
#pragma unroll
    for (int nt = 0; nt < 8; ++nt) { bb1[nt] = b1[nt * 16 + l15]; bb2[nt] = b2[nt * 16 + l15]; }

    __syncthreads();  // done reading W1
    bf16x8 a2[2][4];
#pragma unroll
    for (int mi = 0; mi < 2; ++mi) {
#pragma unroll
        for (int nt = 0; nt < 8; ++nt)
#pragma unroll
            for (int rg = 0; rg < 4; ++rg) {
                float v = acc1[mi][nt][rg] * 0.5f + bb1[nt];
                v = v > 0.f ? v : 0.f;
                sw[(q * 4 + rg) * 136 + nt * 16 + l15] = f2b(v);
            }
#pragma unroll
        for (int kt = 0; kt < 4; ++kt)
            a2[mi][kt] = *(const bf16x8*)(sw + l15 * 136 + kt * 32 + q * 8);
    }
    __syncthreads();  // done with scratch
    {
        const uint4* s = (const uint4*)(wf + 16384);
        uint4* d = (uint4*)wlds;
        for (int i = threadIdx.x; i < 2048; i += 256) d[i] = s[i];
    }
    __syncthreads();
    f32x4 acc2[2][8];
#pragma unroll
    for (int mi = 0; mi < 2; ++mi)
#pragma unroll
        for (int nt = 0; nt < 8; ++nt) acc2[mi][nt] = z;
#pragma unroll
    for (int kt = 0; kt < 4; ++kt)
#pragma unroll
        for (int nt = 0; nt < 8; ++nt) {
            bf16x8 b = *(const bf16x8*)(wlds + (kt * 8 + nt) * 512 + lane * 8);
            acc2[0][nt] = mfma16(a2[0][kt], b, acc2[0][nt]);
            acc2[1][nt] = mfma16(a2[1][kt], b, acc2[1][nt]);
        }
    // out layer: per-lane partials over 8 cols, shfl-xor reduce across 16-lane group
    float owp0[8], owp1[8];
#pragma unroll
    for (int nt = 0; nt < 8; ++nt) {
        int k = nt * 16 + l15;
        owp0[nt] = ow[2 * k];
        owp1[nt] = ow[2 * k + 1];
    }
    float ob0 = ob[0], ob1 = ob[1];
#pragma unroll
    for (int mi = 0; mi < 2; ++mi)
#pragma unroll
        for (int rg = 0; rg < 4; ++rg) {
            float p0 = 0.f, p1 = 0.f;
#pragma unroll
            for (int nt = 0; nt < 8; ++nt) {
                float t = acc2[mi][nt][rg] + bb2[nt];
                t = t > 0.f ? t : 0.f;
                p0 += t * owp0[nt];
                p1 += t * owp1[nt];
            }
#pragma unroll
            for (int m = 1; m < 16; m <<= 1) {
                p0 += __shfl_xor(p0, m, 64);
                p1 += __shfl_xor(p1, m, 64);
            }
            if (l15 == 0) {
                int e = eBase + mi * 16 + q * 4 + rg;
                float s0 = p0 + ob0, s1 = p1 + ob1;
                float mx = fmaxf(s0, s1);
                float lse = mx + __logf(__expf(s0 - mx) + __expf(s1 - mx));
                outp[e] = make_float2(s0 - lse, s1 - lse);
            }
        }
}

extern "C" void kernel_launch(void* const* d_in, const int* in_sizes, int n_in,
                              void* d_out, int out_size, void* d_ws, size_t ws_size,
                              hipStream_t stream) {
    const float* x  = (const float*)d_in[0];
    const int* ei   = (const int*)d_in[1];
    const float* wg = (const float*)d_in[2];
    const float* bg = (const float*)d_in[3];
    const float* w1 = (const float*)d_in[4];
    const float* b1 = (const float*)d_in[5];
    const float* w2 = (const float*)d_in[6];
    const float* b2 = (const float*)d_in[7];
    const float* ow = (const float*)d_in[8];
    const float* ob = (const float*)d_in[9];
    float2* out = (float2*)d_out;

    char* ws = (char*)d_ws;
    size_t off = 0;
    auto alloc = [&](size_t bytes) { void* p = ws + off; off += (bytes + 255) & ~(size_t)255; return p; };
    u16* h0      = (u16*)alloc((size_t)NN * DH * 2);   // h0pre; reused as h2
    u16* hA      = (u16*)alloc((size_t)NN * DH * 2);
    int* csr     = (int*)alloc((size_t)NE * 4);
    int* cnt     = (int*)alloc((size_t)NN * 4);
    int* cursor  = (int*)alloc((size_t)NN * 4);
    int* rowptr  = (int*)alloc((size_t)(NN + 1) * 4);
    float* dinv  = (float*)alloc((size_t)NN * 4);
    u16* w12f    = (u16*)alloc(65536);
    u16* wgf     = (u16*)alloc(65536);
    u16* h2      = h0;  // alias: h0pre dead after aggregation

    hipMemsetAsync(cnt, 0, (size_t)NN * 4, stream);
    k_prep_w<<<32, 256, 0, stream>>>(w1, w2, wg, w12f, wgf);
    k_hist<<<NE / 256, 256, 0, stream>>>(ei + NE, cnt);
    k_scan<<<1, 1024, 0, stream>>>(cnt, rowptr, cursor, dinv);
    k_fill<<<NE / 256, 256, 0, stream>>>(ei, ei + NE, cursor, csr);
    k_gemm_x<<<(NN + 127) / 128, 256, 0, stream>>>(x, wgf, dinv, h0);
    k_aggregate<<<NN / 4, 256, 0, stream>>>(h0, dinv, rowptr, csr, bg, hA);
    k_node_mlp<<<(NN + 127) / 128, 256, 0, stream>>>(hA, w12f, b1, b2, h2);
    k_edge_mlp<<<NE / 128, 256, 0, stream>>>(h2, ei, w12f, b1, b2, ow, ob, out);
}

// Round 4
// 398.356 us; speedup vs baseline: 1.3780x; 1.0531x over previous
//
#include <hip/hip_runtime.h>

#define NN 50000
#define NE 800000
#define DIN 256
#define DH 128

typedef float f32x4 __attribute__((ext_vector_type(4)));
typedef __bf16 bf16x8 __attribute__((ext_vector_type(8)));
typedef unsigned short u16;
typedef unsigned int u32;

__device__ __forceinline__ u16 f2b(float f) { return __builtin_bit_cast(u16, (__bf16)f); }
__device__ __forceinline__ float lo_f(u32 u) { return (float)__builtin_bit_cast(__bf16, (u16)(u & 0xFFFFu)); }
__device__ __forceinline__ float hi_f(u32 u) { return (float)__builtin_bit_cast(__bf16, (u16)(u >> 16)); }

__device__ __forceinline__ f32x4 mfma16(bf16x8 a, bf16x8 b, f32x4 c) {
    return __builtin_amdgcn_mfma_f32_16x16x32_bf16(a, b, c, 0, 0, 0);
}

// ---------------- weight pre-swizzle (fp32 -> bf16 B-fragment order) ----------------
// lane l holds B[k = kt*32 + (l>>4)*8 + j][n = nt*16 + (l&15)], j=0..7
// dst[( (kt*8+nt)*64 + lane )*8 + j]
__global__ void k_prep_w(const float* __restrict__ w1, const float* __restrict__ w2,
                         const float* __restrict__ wg,
                         u16* __restrict__ w12f, u16* __restrict__ wgf) {
    int t = blockIdx.x * 256 + threadIdx.x;  // 0..8191
    const float* src; u16* dst; int id;
    if (t < 2048)      { src = w1; dst = w12f;          id = t; }
    else if (t < 4096) { src = w2; dst = w12f + 16384;  id = t - 2048; }
    else               { src = wg; dst = wgf;           id = t - 4096; }
    int lane = id & 63, frag = id >> 6;
    int kt = frag >> 3, nt = frag & 7;
    int k0 = kt * 32 + (lane >> 4) * 8, n = nt * 16 + (lane & 15);
    u16 v[8];
#pragma unroll
    for (int j = 0; j < 8; ++j) v[j] = f2b(src[(k0 + j) * 128 + n]);
#pragma unroll
    for (int j = 0; j < 8; ++j) dst[id * 8 + j] = v[j];
}

// ---------------- degree histogram ----------------
__global__ void k_hist(const int* __restrict__ dst, int* __restrict__ cnt) {
    int e = blockIdx.x * 256 + threadIdx.x;
    atomicAdd(&cnt[dst[e]], 1);
}

// ---------------- exclusive scan + dinv (single block, 1024 threads) ----------------
__global__ void k_scan(const int* __restrict__ cnt, int* __restrict__ rowptr,
                       int* __restrict__ cursor, float* __restrict__ dinv) {
    __shared__ int part[1024];
    int t = threadIdx.x;
    const int CH = (NN + 1023) / 1024;  // 49
    int lo = t * CH, hi = lo + CH; if (hi > NN) hi = NN; if (lo > NN) lo = NN;
    int s = 0;
#pragma unroll 7
    for (int i = lo; i < hi; ++i) {
        int c = cnt[i];
        s += c;
        dinv[i] = rsqrtf((float)c + 1.0f);  // +1 self loop
    }
    part[t] = s;
    __syncthreads();
    for (int off = 1; off < 1024; off <<= 1) {
        int v = part[t];
        int add = (t >= off) ? part[t - off] : 0;
        __syncthreads();
        part[t] = v + add;
        __syncthreads();
    }
    int run = (t == 0) ? 0 : part[t - 1];
#pragma unroll 7
    for (int i = lo; i < hi; ++i) { rowptr[i] = run; cursor[i] = run; run += cnt[i]; }
    if (t == 1023) rowptr[NN] = run;
}

__global__ void k_fill(const int* __restrict__ src, const int* __restrict__ dst,
                       int* __restrict__ cursor, int* __restrict__ csr) {
    int e = blockIdx.x * 256 + threadIdx.x;
    int p = atomicAdd(&cursor[dst[e]], 1);
    csr[p] = src[e];
}

// ---------------- h0pre = (x @ W_gcn) * dinv[row]  (fp32 x -> bf16 MFMA) ----------------
__global__ __launch_bounds__(256) void k_gemm_x(const float* __restrict__ x,
                                                const u16* __restrict__ wgf,
                                                const float* __restrict__ dinv,
                                                u16* __restrict__ h0pre) {
    int wave = threadIdx.x >> 6, lane = threadIdx.x & 63;
    int l15 = lane & 15, q = lane >> 4;
    int rowBase = blockIdx.x * 128 + wave * 32;

    bf16x8 a[2][8];
#pragma unroll
    for (int mi = 0; mi < 2; ++mi) {
        int r = rowBase + mi * 16 + l15; if (r >= NN) r = NN - 1;
        const float* rp = x + (size_t)r * DIN + q * 8;
#pragma unroll
        for (int kt = 0; kt < 8; ++kt) {
            f32x4 f0 = *(const f32x4*)(rp + kt * 32);
            f32x4 f1 = *(const f32x4*)(rp + kt * 32 + 4);
            bf16x8 aa;
#pragma unroll
            for (int j = 0; j < 4; ++j) { aa[j] = (__bf16)f0[j]; aa[j + 4] = (__bf16)f1[j]; }
            a[mi][kt] = aa;
        }
    }
    f32x4 z = {0.f, 0.f, 0.f, 0.f};
    f32x4 acc[2][8];
#pragma unroll
    for (int mi = 0; mi < 2; ++mi)
#pragma unroll
        for (int nt = 0; nt < 8; ++nt) acc[mi][nt] = z;

#pragma unroll
    for (int kt = 0; kt < 8; ++kt)
#pragma unroll
        for (int nt = 0; nt < 8; ++nt) {
            bf16x8 b = *(const bf16x8*)(wgf + ((kt * 8 + nt) * 64 + lane) * 8);
            acc[0][nt] = mfma16(a[0][kt], b, acc[0][nt]);
            acc[1][nt] = mfma16(a[1][kt], b, acc[1][nt]);
        }
#pragma unroll
    for (int mi = 0; mi < 2; ++mi)
#pragma unroll
        for (int rg = 0; rg < 4; ++rg) {
            int r = rowBase + mi * 16 + q * 4 + rg;
            if (r < NN) {
                float dv = dinv[r];
#pragma unroll
                for (int nt = 0; nt < 8; ++nt)
                    h0pre[r * DH + nt * 16 + l15] = f2b(acc[mi][nt][rg] * dv);
            }
        }
}

// ---------------- GCN aggregate ----------------
__global__ __launch_bounds__(256) void k_aggregate(const u16* __restrict__ h0pre,
                                                   const float* __restrict__ dinv,
                                                   const int* __restrict__ rowptr,
                                                   const int* __restrict__ csr,
                                                   const float* __restrict__ bg,
                                                   u16* __restrict__ hA) {
    int v = blockIdx.x * 4 + (threadIdx.x >> 6);
    int lane = threadIdx.x & 63;
    const u32* h = (const u32*)h0pre;
    u32 su = h[v * 64 + lane];
    float a0 = lo_f(su), a1 = hi_f(su);  // self-loop (dv^2*h = dv*h0pre folded)
    float b0 = 0.f, b1 = 0.f, c0 = 0.f, c1 = 0.f, d0 = 0.f, d1 = 0.f;
    int beg = rowptr[v], end = rowptr[v + 1];
    int j = beg;
    for (; j + 4 <= end; j += 4) {
        int s0 = csr[j], s1 = csr[j + 1], s2 = csr[j + 2], s3 = csr[j + 3];
        u32 u0 = h[s0 * 64 + lane];
        u32 u1 = h[s1 * 64 + lane];
        u32 u2 = h[s2 * 64 + lane];
        u32 u3 = h[s3 * 64 + lane];
        a0 += lo_f(u0); a1 += hi_f(u0);
        b0 += lo_f(u1); b1 += hi_f(u1);
        c0 += lo_f(u2); c1 += hi_f(u2);
        d0 += lo_f(u3); d1 += hi_f(u3);
    }
    for (; j < end; ++j) {
        int s = csr[j];
        u32 u = h[s * 64 + lane];
        a0 += lo_f(u); a1 += hi_f(u);
    }
    a0 += b0 + c0 + d0; a1 += b1 + c1 + d1;
    float dv = dinv[v];
    float bg0 = bg[2 * lane], bg1 = bg[2 * lane + 1];
    a0 = fmaxf(a0 * dv + bg0, 0.f);
    a1 = fmaxf(a1 * dv + bg1, 0.f);
    ((u32*)hA)[v * 64 + lane] = (u32)f2b(a0) | ((u32)f2b(a1) << 16);
}

// ---------------- fused node MLP + g-precompute ----------------
// g = (relu(relu(hA@W1+b1)@W2+b2)) @ W1   (g row-major bf16; bias b1 added per-edge)
__global__ __launch_bounds__(256) void k_node_mlp(const u16* __restrict__ hA,
                                                  const u16* __restrict__ wf,
                                                  const float* __restrict__ b1,
                                                  const float* __restrict__ b2,
                                                  u16* __restrict__ g) {
    __shared__ __align__(16) u16 wlds[16384];     // weight buffer (W1 -> W2 -> W1)
    __shared__ __align__(16) u16 sct[4][2176];    // dedicated per-wave transpose scratch
    {
        const uint4* s = (const uint4*)wf;
        uint4* d = (uint4*)wlds;
        for (int i = threadIdx.x; i < 2048; i += 256) d[i] = s[i];
    }
    __syncthreads();
    int wave = threadIdx.x >> 6, lane = threadIdx.x & 63;
    int l15 = lane & 15, q = lane >> 4;
    int rowBase = blockIdx.x * 128 + wave * 32;
    u16* sw = sct[wave];

    bf16x8 a[2][4];
#pragma unroll
    for (int mi = 0; mi < 2; ++mi) {
        int r = rowBase + mi * 16 + l15; if (r >= NN) r = NN - 1;
        const u16* rp = hA + r * DH + q * 8;
#pragma unroll
        for (int kt = 0; kt < 4; ++kt) a[mi][kt] = *(const bf16x8*)(rp + kt * 32);
    }
    f32x4 z = {0.f, 0.f, 0.f, 0.f};
    f32x4 acc1[2][8];
#pragma unroll
    for (int mi = 0; mi < 2; ++mi)
#pragma unroll
        for (int nt = 0; nt < 8; ++nt) acc1[mi][nt] = z;
#pragma unroll
    for (int kt = 0; kt < 4; ++kt)
#pragma unroll
        for (int nt = 0; nt < 8; ++nt) {
            bf16x8 b = *(const bf16x8*)(wlds + (kt * 8 + nt) * 512 + lane * 8);
            acc1[0][nt] = mfma16(a[0][kt], b, acc1[0][nt]);
            acc1[1][nt] = mfma16(a[1][kt], b, acc1[1][nt]);
        }
    float bb1[8], bb2[8];
#pragma unroll
    for (int nt = 0; nt < 8; ++nt) { bb1[nt] = b1[nt * 16 + l15]; bb2[nt] = b2[nt * 16 + l15]; }

    // transpose t1 (C-layout) -> A-frags via dedicated scratch (no barrier: per-wave)
    bf16x8 a2[2][4];
#pragma unroll
    for (int mi = 0; mi < 2; ++mi) {
#pragma unroll
        for (int nt = 0; nt < 8; ++nt)
#pragma unroll
            for (int rg = 0; rg < 4; ++rg) {
                float v = acc1[mi][nt][rg] + bb1[nt];
                v = v > 0.f ? v : 0.f;
                sw[(q * 4 + rg) * 136 + nt * 16 + l15] = f2b(v);
            }
#pragma unroll
        for (int kt = 0; kt < 4; ++kt)
            a2[mi][kt] = *(const bf16x8*)(sw + l15 * 136 + kt * 32 + q * 8);
    }
    __syncthreads();  // all waves done reading W1
    {
        const uint4* s = (const uint4*)(wf + 16384);
        uint4* d = (uint4*)wlds;
        for (int i = threadIdx.x; i < 2048; i += 256) d[i] = s[i];
    }
    __syncthreads();
    f32x4 acc2[2][8];
#pragma unroll
    for (int mi = 0; mi < 2; ++mi)
#pragma unroll
        for (int nt = 0; nt < 8; ++nt) acc2[mi][nt] = z;
#pragma unroll
    for (int kt = 0; kt < 4; ++kt)
#pragma unroll
        for (int nt = 0; nt < 8; ++nt) {
            bf16x8 b = *(const bf16x8*)(wlds + (kt * 8 + nt) * 512 + lane * 8);
            acc2[0][nt] = mfma16(a2[0][kt], b, acc2[0][nt]);
            acc2[1][nt] = mfma16(a2[1][kt], b, acc2[1][nt]);
        }
    // transpose h2 -> A-frags (per-wave scratch, no barrier)
    bf16x8 a3[2][4];
#pragma unroll
    for (int mi = 0; mi < 2; ++mi) {
#pragma unroll
        for (int nt = 0; nt < 8; ++nt)
#pragma unroll
            for (int rg = 0; rg < 4; ++rg) {
                float v = acc2[mi][nt][rg] + bb2[nt];
                v = v > 0.f ? v : 0.f;
                sw[(q * 4 + rg) * 136 + nt * 16 + l15] = f2b(v);
            }
#pragma unroll
        for (int kt = 0; kt < 4; ++kt)
            a3[mi][kt] = *(const bf16x8*)(sw + l15 * 136 + kt * 32 + q * 8);
    }
    __syncthreads();  // all waves done reading W2
    {
        const uint4* s = (const uint4*)wf;  // reload W1
        uint4* d = (uint4*)wlds;
        for (int i = threadIdx.x; i < 2048; i += 256) d[i] = s[i];
    }
    __syncthreads();
    f32x4 acc3[2][8];
#pragma unroll
    for (int mi = 0; mi < 2; ++mi)
#pragma unroll
        for (int nt = 0; nt < 8; ++nt) acc3[mi][nt] = z;
#pragma unroll
    for (int kt = 0; kt < 4; ++kt)
#pragma unroll
        for (int nt = 0; nt < 8; ++nt) {
            bf16x8 b = *(const bf16x8*)(wlds + (kt * 8 + nt) * 512 + lane * 8);
            acc3[0][nt] = mfma16(a3[0][kt], b, acc3[0][nt]);
            acc3[1][nt] = mfma16(a3[1][kt], b, acc3[1][nt]);
        }
#pragma unroll
    for (int mi = 0; mi < 2; ++mi)
#pragma unroll
        for (int nt = 0; nt < 8; ++nt)
#pragma unroll
            for (int rg = 0; rg < 4; ++rg) {
                int r = rowBase + mi * 16 + q * 4 + rg;
                if (r < NN) g[r * DH + nt * 16 + l15] = f2b(acc3[mi][nt][rg]);
            }
}

// ---------------- edge kernel: t1 built in-register from g, one GEMM, out + log_softmax ----------------
__global__ __launch_bounds__(256) void k_edge_mlp(const u16* __restrict__ g,
                                                  const int* __restrict__ ei,
                                                  const u16* __restrict__ wf,
                                                  const float* __restrict__ b1,
                                                  const float* __restrict__ b2,
                                                  const float* __restrict__ ow,
                                                  const float* __restrict__ ob,
                                                  float2* __restrict__ outp) {
    __shared__ __align__(16) u16 wlds[16384];  // W2 only
    // stage W2 (independent of gathers below)
    {
        const uint4* s = (const uint4*)(wf + 16384);
        uint4* d = (uint4*)wlds;
        for (int i = threadIdx.x; i < 2048; i += 256) d[i] = s[i];
    }
    int wave = threadIdx.x >> 6, lane = threadIdx.x & 63;
    int l15 = lane & 15, q = lane >> 4;
    int eBase = blockIdx.x * 128 + wave * 32;

    int e0 = eBase + l15, e1 = eBase + 16 + l15;
    const u16* pgs0 = g + ei[e0] * DH + q * 8;
    const u16* pgd0 = g + ei[NE + e0] * DH + q * 8;
    const u16* pgs1 = g + ei[e1] * DH + q * 8;
    const u16* pgd1 = g + ei[NE + e1] * DH + q * 8;

    // gather g fragments (A-layout positions: k = kt*32 + q*8 + j)
    bf16x8 gs[2][4], gd[2][4];
#pragma unroll
    for (int kt = 0; kt < 4; ++kt) {
        gs[0][kt] = *(const bf16x8*)(pgs0 + kt * 32);
        gd[0][kt] = *(const bf16x8*)(pgd0 + kt * 32);
        gs[1][kt] = *(const bf16x8*)(pgs1 + kt * 32);
        gd[1][kt] = *(const bf16x8*)(pgd1 + kt * 32);
    }
    // b1 at k = kt*32 + q*8 + j
    float b1v[4][8];
#pragma unroll
    for (int kt = 0; kt < 4; ++kt) {
        f32x4 u0 = *(const f32x4*)(b1 + kt * 32 + q * 8);
        f32x4 u1 = *(const f32x4*)(b1 + kt * 32 + q * 8 + 4);
#pragma unroll
        for (int j = 0; j < 4; ++j) { b1v[kt][j] = u0[j]; b1v[kt][j + 4] = u1[j]; }
    }
    // t1 = relu(0.5*(g[s]+g[d]) + b1), directly in A-fragment layout
    bf16x8 a2[2][4];
#pragma unroll
    for (int mi = 0; mi < 2; ++mi)
#pragma unroll
        for (int kt = 0; kt < 4; ++kt) {
            bf16x8 r;
#pragma unroll
            for (int j = 0; j < 8; ++j) {
                float t = 0.5f * ((float)gs[mi][kt][j] + (float)gd[mi][kt][j]) + b1v[kt][j];
                r[j] = (__bf16)(t > 0.f ? t : 0.f);
            }
            a2[mi][kt] = r;
        }
    float bb2[8];
#pragma unroll
    for (int nt = 0; nt < 8; ++nt) bb2[nt] = b2[nt * 16 + l15];
    float owp0[8], owp1[8];
#pragma unroll
    for (int nt = 0; nt < 8; ++nt) {
        int k = nt * 16 + l15;
        owp0[nt] = ow[2 * k];
        owp1[nt] = ow[2 * k + 1];
    }
    float ob0 = ob[0], ob1 = ob[1];

    __syncthreads();  // W2 staged
    f32x4 z = {0.f, 0.f, 0.f, 0.f};
    f32x4 acc2[2][8];
#pragma unroll
    for (int mi = 0; mi < 2; ++mi)
#pragma unroll
        for (int nt = 0; nt < 8; ++nt) acc2[mi][nt] = z;
#pragma unroll
    for (int kt = 0; kt < 4; ++kt)
#pragma unroll
        for (int nt = 0; nt < 8; ++nt) {
            bf16x8 b = *(const bf16x8*)(wlds + (kt * 8 + nt) * 512 + lane * 8);
            acc2[0][nt] = mfma16(a2[0][kt], b, acc2[0][nt]);
            acc2[1][nt] = mfma16(a2[1][kt], b, acc2[1][nt]);
        }
    // out layer + log_softmax
#pragma unroll
    for (int mi = 0; mi < 2; ++mi)
#pragma unroll
        for (int rg = 0; rg < 4; ++rg) {
            float p0 = 0.f, p1 = 0.f;
#pragma unroll
            for (int nt = 0; nt < 8; ++nt) {
                float t = acc2[mi][nt][rg] + bb2[nt];
                t = t > 0.f ? t : 0.f;
                p0 += t * owp0[nt];
                p1 += t * owp1[nt];
            }
#pragma unroll
            for (int m = 1; m < 16; m <<= 1) {
                p0 += __shfl_xor(p0, m, 64);
                p1 += __shfl_xor(p1, m, 64);
            }
            if (l15 == 0) {
                int e = eBase + mi * 16 + q * 4 + rg;
                float s0 = p0 + ob0, s1 = p1 + ob1;
                float mx = fmaxf(s0, s1);
                float lse = mx + __logf(__expf(s0 - mx) + __expf(s1 - mx));
                outp[e] = make_float2(s0 - lse, s1 - lse);
            }
        }
}

extern "C" void kernel_launch(void* const* d_in, const int* in_sizes, int n_in,
                              void* d_out, int out_size, void* d_ws, size_t ws_size,
                              hipStream_t stream) {
    const float* x  = (const float*)d_in[0];
    const int* ei   = (const int*)d_in[1];
    const float* wg = (const float*)d_in[2];
    const float* bg = (const float*)d_in[3];
    const float* w1 = (const float*)d_in[4];
    const float* b1 = (const float*)d_in[5];
    const float* w2 = (const float*)d_in[6];
    const float* b2 = (const float*)d_in[7];
    const float* ow = (const float*)d_in[8];
    const float* ob = (const float*)d_in[9];
    float2* out = (float2*)d_out;

    char* ws = (char*)d_ws;
    size_t off = 0;
    auto alloc = [&](size_t bytes) { void* p = ws + off; off += (bytes + 255) & ~(size_t)255; return p; };
    u16* h0      = (u16*)alloc((size_t)NN * DH * 2);   // h0pre; reused as g
    u16* hA      = (u16*)alloc((size_t)NN * DH * 2);
    int* csr     = (int*)alloc((size_t)NE * 4);
    int* cnt     = (int*)alloc((size_t)NN * 4);
    int* cursor  = (int*)alloc((size_t)NN * 4);
    int* rowptr  = (int*)alloc((size_t)(NN + 1) * 4);
    float* dinv  = (float*)alloc((size_t)NN * 4);
    u16* w12f    = (u16*)alloc(65536);
    u16* wgf     = (u16*)alloc(65536);
    u16* g       = h0;  // alias: h0pre dead after aggregation

    hipMemsetAsync(cnt, 0, (size_t)NN * 4, stream);
    k_prep_w<<<32, 256, 0, stream>>>(w1, w2, wg, w12f, wgf);
    k_hist<<<NE / 256, 256, 0, stream>>>(ei + NE, cnt);
    k_scan<<<1, 1024, 0, stream>>>(cnt, rowptr, cursor, dinv);
    k_fill<<<NE / 256, 256, 0, stream>>>(ei, ei + NE, cursor, csr);
    k_gemm_x<<<(NN + 127) / 128, 256, 0, stream>>>(x, wgf, dinv, h0);
    k_aggregate<<<NN / 4, 256, 0, stream>>>(h0, dinv, rowptr, csr, bg, hA);
    k_node_mlp<<<(NN + 127) / 128, 256, 0, stream>>>(hA, w12f, b1, b2, g);
    k_edge_mlp<<<NE / 128, 256, 0, stream>>>(g, ei, w12f, b1, b2, ow, ob, out);
}

// Round 5
// 377.335 us; speedup vs baseline: 1.4547x; 1.0557x over previous
//
#include <hip/hip_runtime.h>

#define NN 50000
#define NE 800000
#define DIN 256
#define DH 128

typedef float f32x4 __attribute__((ext_vector_type(4)));
typedef __bf16 bf16x8 __attribute__((ext_vector_type(8)));
typedef unsigned short u16;
typedef unsigned int u32;

__device__ __forceinline__ u16 f2b(float f) { return __builtin_bit_cast(u16, (__bf16)f); }
__device__ __forceinline__ float lo_f(u32 u) { return (float)__builtin_bit_cast(__bf16, (u16)(u & 0xFFFFu)); }
__device__ __forceinline__ float hi_f(u32 u) { return (float)__builtin_bit_cast(__bf16, (u16)(u >> 16)); }

__device__ __forceinline__ f32x4 mfma16(bf16x8 a, bf16x8 b, f32x4 c) {
    return __builtin_amdgcn_mfma_f32_16x16x32_bf16(a, b, c, 0, 0, 0);
}

// ---------------- merged: weight pre-swizzle (32 blocks) + degree histogram (3125 blocks) ----------------
// B-frag layout: lane l holds B[k = kt*32 + (l>>4)*8 + j][n = nt*16 + (l&15)], j=0..7
// dst[( (kt*8+nt)*64 + lane )*8 + j]
__global__ void k_prep_hist(const float* __restrict__ w1, const float* __restrict__ w2,
                            const float* __restrict__ wg,
                            u16* __restrict__ w12f, u16* __restrict__ wgf,
                            const int* __restrict__ dste, int* __restrict__ cnt) {
    int b = blockIdx.x;
    if (b < 32) {
        int t = b * 256 + threadIdx.x;  // 0..8191
        const float* src; u16* dst; int id;
        if (t < 2048)      { src = w1; dst = w12f;          id = t; }
        else if (t < 4096) { src = w2; dst = w12f + 16384;  id = t - 2048; }
        else               { src = wg; dst = wgf;           id = t - 4096; }
        int lane = id & 63, frag = id >> 6;
        int kt = frag >> 3, nt = frag & 7;
        int k0 = kt * 32 + (lane >> 4) * 8, n = nt * 16 + (lane & 15);
        u16 v[8];
#pragma unroll
        for (int j = 0; j < 8; ++j) v[j] = f2b(src[(k0 + j) * 128 + n]);
#pragma unroll
        for (int j = 0; j < 8; ++j) dst[id * 8 + j] = v[j];
    } else {
        int e = (b - 32) * 256 + threadIdx.x;
        atomicAdd(&cnt[dste[e]], 1);
    }
}

// ---------------- exclusive scan + dinv (single block, 1024 threads) ----------------
__global__ void k_scan(const int* __restrict__ cnt, int* __restrict__ rowptr,
                       int* __restrict__ cursor, float* __restrict__ dinv) {
    __shared__ int part[1024];
    int t = threadIdx.x;
    const int CH = (NN + 1023) / 1024;  // 49
    int lo = t * CH, hi = lo + CH; if (hi > NN) hi = NN; if (lo > NN) lo = NN;
    int s = 0;
#pragma unroll 7
    for (int i = lo; i < hi; ++i) {
        int c = cnt[i];
        s += c;
        dinv[i] = rsqrtf((float)c + 1.0f);  // +1 self loop
    }
    part[t] = s;
    __syncthreads();
    for (int off = 1; off < 1024; off <<= 1) {
        int v = part[t];
        int add = (t >= off) ? part[t - off] : 0;
        __syncthreads();
        part[t] = v + add;
        __syncthreads();
    }
    int run = (t == 0) ? 0 : part[t - 1];
#pragma unroll 7
    for (int i = lo; i < hi; ++i) { rowptr[i] = run; cursor[i] = run; run += cnt[i]; }
    if (t == 1023) rowptr[NN] = run;
}

__global__ void k_fill(const int* __restrict__ src, const int* __restrict__ dst,
                       int* __restrict__ cursor, int* __restrict__ csr) {
    int e = blockIdx.x * 256 + threadIdx.x;
    int p = atomicAdd(&cursor[dst[e]], 1);
    csr[p] = src[e];
}

// ---------------- h0pre = (x @ W_gcn) * dinv[row]  (fp32 x -> bf16 MFMA) ----------------
__global__ __launch_bounds__(256) void k_gemm_x(const float* __restrict__ x,
                                                const u16* __restrict__ wgf,
                                                const float* __restrict__ dinv,
                                                u16* __restrict__ h0pre) {
    int wave = threadIdx.x >> 6, lane = threadIdx.x & 63;
    int l15 = lane & 15, q = lane >> 4;
    int rowBase = blockIdx.x * 128 + wave * 32;

    bf16x8 a[2][8];
#pragma unroll
    for (int mi = 0; mi < 2; ++mi) {
        int r = rowBase + mi * 16 + l15; if (r >= NN) r = NN - 1;
        const float* rp = x + (size_t)r * DIN + q * 8;
#pragma unroll
        for (int kt = 0; kt < 8; ++kt) {
            f32x4 f0 = *(const f32x4*)(rp + kt * 32);
            f32x4 f1 = *(const f32x4*)(rp + kt * 32 + 4);
            bf16x8 aa;
#pragma unroll
            for (int j = 0; j < 4; ++j) { aa[j] = (__bf16)f0[j]; aa[j + 4] = (__bf16)f1[j]; }
            a[mi][kt] = aa;
        }
    }
    f32x4 z = {0.f, 0.f, 0.f, 0.f};
    f32x4 acc[2][8];
#pragma unroll
    for (int mi = 0; mi < 2; ++mi)
#pragma unroll
        for (int nt = 0; nt < 8; ++nt) acc[mi][nt] = z;

#pragma unroll
    for (int kt = 0; kt < 8; ++kt)
#pragma unroll
        for (int nt = 0; nt < 8; ++nt) {
            bf16x8 b = *(const bf16x8*)(wgf + ((kt * 8 + nt) * 64 + lane) * 8);
            acc[0][nt] = mfma16(a[0][kt], b, acc[0][nt]);
            acc[1][nt] = mfma16(a[1][kt], b, acc[1][nt]);
        }
#pragma unroll
    for (int mi = 0; mi < 2; ++mi)
#pragma unroll
        for (int rg = 0; rg < 4; ++rg) {
            int r = rowBase + mi * 16 + q * 4 + rg;
            if (r < NN) {
                float dv = dinv[r];
#pragma unroll
                for (int nt = 0; nt < 8; ++nt)
                    h0pre[r * DH + nt * 16 + l15] = f2b(acc[mi][nt][rg] * dv);
            }
        }
}

// ---------------- GCN aggregate: 8-way ILP gather-reduce ----------------
__global__ __launch_bounds__(256) void k_aggregate(const u16* __restrict__ h0pre,
                                                   const float* __restrict__ dinv,
                                                   const int* __restrict__ rowptr,
                                                   const int* __restrict__ csr,
                                                   const float* __restrict__ bg,
                                                   u16* __restrict__ hA) {
    int v = blockIdx.x * 4 + (threadIdx.x >> 6);
    int lane = threadIdx.x & 63;
    const u32* h = (const u32*)h0pre;
    u32 su = h[v * 64 + lane];
    float p0[8], p1[8];
#pragma unroll
    for (int k = 0; k < 8; ++k) { p0[k] = 0.f; p1[k] = 0.f; }
    p0[0] = lo_f(su); p1[0] = hi_f(su);  // self-loop (dv^2*h = dv*h0pre folded)
    int beg = rowptr[v], end = rowptr[v + 1];
    int j = beg;
    for (; j + 8 <= end; j += 8) {
        int idx[8]; u32 u[8];
#pragma unroll
        for (int k = 0; k < 8; ++k) idx[k] = csr[j + k];
#pragma unroll
        for (int k = 0; k < 8; ++k) u[k] = h[idx[k] * 64 + lane];
#pragma unroll
        for (int k = 0; k < 8; ++k) { p0[k] += lo_f(u[k]); p1[k] += hi_f(u[k]); }
    }
    for (; j + 2 <= end; j += 2) {
        u32 ua = h[csr[j] * 64 + lane];
        u32 ub = h[csr[j + 1] * 64 + lane];
        p0[0] += lo_f(ua); p1[0] += hi_f(ua);
        p0[1] += lo_f(ub); p1[1] += hi_f(ub);
    }
    for (; j < end; ++j) {
        u32 u = h[csr[j] * 64 + lane];
        p0[0] += lo_f(u); p1[0] += hi_f(u);
    }
#pragma unroll
    for (int k = 4; k >= 1; k >>= 1)
#pragma unroll
        for (int m = 0; m < k; ++m) { p0[m] += p0[m + k]; p1[m] += p1[m + k]; }
    float dv = dinv[v];
    float bg0 = bg[2 * lane], bg1 = bg[2 * lane + 1];
    float a0 = fmaxf(p0[0] * dv + bg0, 0.f);
    float a1 = fmaxf(p1[0] * dv + bg1, 0.f);
    ((u32*)hA)[v * 64 + lane] = (u32)f2b(a0) | ((u32)f2b(a1) << 16);
}

// ---------------- fused node MLP + gh-precompute ----------------
// gh = 0.5 * (relu(relu(hA@W1+b1)@W2+b2) @ W1) + 0.5*b1   (so edge t1 = relu(gh_s + gh_d))
__global__ __launch_bounds__(256) void k_node_mlp(const u16* __restrict__ hA,
                                                  const u16* __restrict__ wf,
                                                  const float* __restrict__ b1,
                                                  const float* __restrict__ b2,
                                                  u16* __restrict__ gh) {
    __shared__ __align__(16) u16 wlds[16384];     // weight buffer (W1 -> W2 -> W1)
    __shared__ __align__(16) u16 sct[4][2176];    // per-wave transpose scratch
    {
        const uint4* s = (const uint4*)wf;
        uint4* d = (uint4*)wlds;
        for (int i = threadIdx.x; i < 2048; i += 256) d[i] = s[i];
    }
    __syncthreads();
    int wave = threadIdx.x >> 6, lane = threadIdx.x & 63;
    int l15 = lane & 15, q = lane >> 4;
    int rowBase = blockIdx.x * 128 + wave * 32;
    u16* sw = sct[wave];

    bf16x8 a[2][4];
#pragma unroll
    for (int mi = 0; mi < 2; ++mi) {
        int r = rowBase + mi * 16 + l15; if (r >= NN) r = NN - 1;
        const u16* rp = hA + r * DH + q * 8;
#pragma unroll
        for (int kt = 0; kt < 4; ++kt) a[mi][kt] = *(const bf16x8*)(rp + kt * 32);
    }
    f32x4 z = {0.f, 0.f, 0.f, 0.f};
    f32x4 acc1[2][8];
#pragma unroll
    for (int mi = 0; mi < 2; ++mi)
#pragma unroll
        for (int nt = 0; nt < 8; ++nt) acc1[mi][nt] = z;
#pragma unroll
    for (int kt = 0; kt < 4; ++kt)
#pragma unroll
        for (int nt = 0; nt < 8; ++nt) {
            bf16x8 b = *(const bf16x8*)(wlds + (kt * 8 + nt) * 512 + lane * 8);
            acc1[0][nt] = mfma16(a[0][kt], b, acc1[0][nt]);
            acc1[1][nt] = mfma16(a[1][kt], b, acc1[1][nt]);
        }
    float bb1[8], bb2[8];
#pragma unroll
    for (int nt = 0; nt < 8; ++nt) { bb1[nt] = b1[nt * 16 + l15]; bb2[nt] = b2[nt * 16 + l15]; }

    bf16x8 a2[2][4];
#pragma unroll
    for (int mi = 0; mi < 2; ++mi) {
#pragma unroll
        for (int nt = 0; nt < 8; ++nt)
#pragma unroll
            for (int rg = 0; rg < 4; ++rg) {
                float v = acc1[mi][nt][rg] + bb1[nt];
                v = v > 0.f ? v : 0.f;
                sw[(q * 4 + rg) * 136 + nt * 16 + l15] = f2b(v);
            }
#pragma unroll
        for (int kt = 0; kt < 4; ++kt)
            a2[mi][kt] = *(const bf16x8*)(sw + l15 * 136 + kt * 32 + q * 8);
    }
    __syncthreads();  // all waves done reading W1
    {
        const uint4* s = (const uint4*)(wf + 16384);
        uint4* d = (uint4*)wlds;
        for (int i = threadIdx.x; i < 2048; i += 256) d[i] = s[i];
    }
    __syncthreads();
    f32x4 acc2[2][8];
#pragma unroll
    for (int mi = 0; mi < 2; ++mi)
#pragma unroll
        for (int nt = 0; nt < 8; ++nt) acc2[mi][nt] = z;
#pragma unroll
    for (int kt = 0; kt < 4; ++kt)
#pragma unroll
        for (int nt = 0; nt < 8; ++nt) {
            bf16x8 b = *(const bf16x8*)(wlds + (kt * 8 + nt) * 512 + lane * 8);
            acc2[0][nt] = mfma16(a2[0][kt], b, acc2[0][nt]);
            acc2[1][nt] = mfma16(a2[1][kt], b, acc2[1][nt]);
        }
    bf16x8 a3[2][4];
#pragma unroll
    for (int mi = 0; mi < 2; ++mi) {
#pragma unroll
        for (int nt = 0; nt < 8; ++nt)
#pragma unroll
            for (int rg = 0; rg < 4; ++rg) {
                float v = acc2[mi][nt][rg] + bb2[nt];
                v = v > 0.f ? v : 0.f;
                sw[(q * 4 + rg) * 136 + nt * 16 + l15] = f2b(v);
            }
#pragma unroll
        for (int kt = 0; kt < 4; ++kt)
            a3[mi][kt] = *(const bf16x8*)(sw + l15 * 136 + kt * 32 + q * 8);
    }
    __syncthreads();  // all waves done reading W2
    {
        const uint4* s = (const uint4*)wf;  // reload W1
        uint4* d = (uint4*)wlds;
        for (int i = threadIdx.x; i < 2048; i += 256) d[i] = s[i];
    }
    __syncthreads();
    f32x4 acc3[2][8];
#pragma unroll
    for (int mi = 0; mi < 2; ++mi)
#pragma unroll
        for (int nt = 0; nt < 8; ++nt) acc3[mi][nt] = z;
#pragma unroll
    for (int kt = 0; kt < 4; ++kt)
#pragma unroll
        for (int nt = 0; nt < 8; ++nt) {
            bf16x8 b = *(const bf16x8*)(wlds + (kt * 8 + nt) * 512 + lane * 8);
            acc3[0][nt] = mfma16(a3[0][kt], b, acc3[0][nt]);
            acc3[1][nt] = mfma16(a3[1][kt], b, acc3[1][nt]);
        }
#pragma unroll
    for (int mi = 0; mi < 2; ++mi)
#pragma unroll
        for (int nt = 0; nt < 8; ++nt)
#pragma unroll
            for (int rg = 0; rg < 4; ++rg) {
                int r = rowBase + mi * 16 + q * 4 + rg;
                if (r < NN)
                    gh[r * DH + nt * 16 + l15] = f2b(0.5f * acc3[mi][nt][rg] + 0.5f * bb1[nt]);
            }
}

// ---------------- edge kernel: 64 edges/wave, t1 = relu(gh_s + gh_d), one GEMM, out + log_softmax ----------------
__global__ __launch_bounds__(256, 3) void k_edge_mlp(const u16* __restrict__ gh,
                                                     const int* __restrict__ ei,
                                                     const u16* __restrict__ wf,
                                                     const float* __restrict__ b2,
                                                     const float* __restrict__ ow,
                                                     const float* __restrict__ ob,
                                                     float2* __restrict__ outp) {
    __shared__ __align__(16) u16 wlds[16384];  // W2 only
    {
        const uint4* s = (const uint4*)(wf + 16384);
        uint4* d = (uint4*)wlds;
        for (int i = threadIdx.x; i < 2048; i += 256) d[i] = s[i];
    }
    int wave = threadIdx.x >> 6, lane = threadIdx.x & 63;
    int l15 = lane & 15, q = lane >> 4;
    int eBase = blockIdx.x * 256 + wave * 64;

    int se[4], de[4];
#pragma unroll
    for (int ti = 0; ti < 4; ++ti) {
        int e = eBase + ti * 16 + l15;
        se[ti] = ei[e];
        de[ti] = ei[NE + e];
    }
    // issue gathers for first two tiles
    bf16x8 gsA[4], gdA[4], gsB[4], gdB[4];
    {
        const u16* ps = gh + se[0] * DH + q * 8;
        const u16* pd = gh + de[0] * DH + q * 8;
#pragma unroll
        for (int kt = 0; kt < 4; ++kt) {
            gsA[kt] = *(const bf16x8*)(ps + kt * 32);
            gdA[kt] = *(const bf16x8*)(pd + kt * 32);
        }
    }
    {
        const u16* ps = gh + se[1] * DH + q * 8;
        const u16* pd = gh + de[1] * DH + q * 8;
#pragma unroll
        for (int kt = 0; kt < 4; ++kt) {
            gsB[kt] = *(const bf16x8*)(ps + kt * 32);
            gdB[kt] = *(const bf16x8*)(pd + kt * 32);
        }
    }
    float bb2[8], owp0[8], owp1[8];
#pragma unroll
    for (int nt = 0; nt < 8; ++nt) {
        int k = nt * 16 + l15;
        bb2[nt] = b2[k];
        owp0[nt] = ow[2 * k];
        owp1[nt] = ow[2 * k + 1];
    }
    float ob0 = ob[0], ob1 = ob[1];
    __syncthreads();  // W2 staged (gathers already in flight)
    f32x4 z = {0.f, 0.f, 0.f, 0.f};

#pragma unroll
    for (int ti = 0; ti < 4; ++ti) {
        // current tile's fragments (A/B ping-pong), prefetch tile ti+2 into the slot being vacated
        bf16x8 fs[4], fd[4];
#pragma unroll
        for (int kt = 0; kt < 4; ++kt) {
            fs[kt] = (ti & 1) ? gsB[kt] : gsA[kt];
            fd[kt] = (ti & 1) ? gdB[kt] : gdA[kt];
        }
        if (ti + 2 < 4) {
            const u16* ps = gh + se[ti + 2] * DH + q * 8;
            const u16* pd = gh + de[ti + 2] * DH + q * 8;
#pragma unroll
            for (int kt = 0; kt < 4; ++kt) {
                if (ti & 1) { gsB[kt] = *(const bf16x8*)(ps + kt * 32); gdB[kt] = *(const bf16x8*)(pd + kt * 32); }
                else        { gsA[kt] = *(const bf16x8*)(ps + kt * 32); gdA[kt] = *(const bf16x8*)(pd + kt * 32); }
            }
        }
        // t1 = relu(gh_s + gh_d) directly in A-fragment layout
        bf16x8 a2[4];
#pragma unroll
        for (int kt = 0; kt < 4; ++kt) {
            bf16x8 r;
#pragma unroll
            for (int j = 0; j < 8; ++j) {
                float t = (float)fs[kt][j] + (float)fd[kt][j];
                r[j] = (__bf16)(t > 0.f ? t : 0.f);
            }
            a2[kt] = r;
        }
        f32x4 acc2[8];
#pragma unroll
        for (int nt = 0; nt < 8; ++nt) acc2[nt] = z;
#pragma unroll
        for (int kt = 0; kt < 4; ++kt)
#pragma unroll
            for (int nt = 0; nt < 8; ++nt) {
                bf16x8 b = *(const bf16x8*)(wlds + (kt * 8 + nt) * 512 + lane * 8);
                acc2[nt] = mfma16(a2[kt], b, acc2[nt]);
            }
        // out layer + log_softmax
#pragma unroll
        for (int rg = 0; rg < 4; ++rg) {
            float p0 = 0.f, p1 = 0.f;
#pragma unroll
            for (int nt = 0; nt < 8; ++nt) {
                float t = acc2[nt][rg] + bb2[nt];
                t = t > 0.f ? t : 0.f;
                p0 += t * owp0[nt];
                p1 += t * owp1[nt];
            }
#pragma unroll
            for (int m = 1; m < 16; m <<= 1) {
                p0 += __shfl_xor(p0, m, 64);
                p1 += __shfl_xor(p1, m, 64);
            }
            if (l15 == 0) {
                int e = eBase + ti * 16 + q * 4 + rg;
                float s0 = p0 + ob0, s1 = p1 + ob1;
                float mx = fmaxf(s0, s1);
                float lse = mx + __logf(__expf(s0 - mx) + __expf(s1 - mx));
                outp[e] = make_float2(s0 - lse, s1 - lse);
            }
        }
    }
}

extern "C" void kernel_launch(void* const* d_in, const int* in_sizes, int n_in,
                              void* d_out, int out_size, void* d_ws, size_t ws_size,
                              hipStream_t stream) {
    const float* x  = (const float*)d_in[0];
    const int* ei   = (const int*)d_in[1];
    const float* wg = (const float*)d_in[2];
    const float* bg = (const float*)d_in[3];
    const float* w1 = (const float*)d_in[4];
    const float* b1 = (const float*)d_in[5];
    const float* w2 = (const float*)d_in[6];
    const float* b2 = (const float*)d_in[7];
    const float* ow = (const float*)d_in[8];
    const float* ob = (const float*)d_in[9];
    float2* out = (float2*)d_out;

    char* ws = (char*)d_ws;
    size_t off = 0;
    auto alloc = [&](size_t bytes) { void* p = ws + off; off += (bytes + 255) & ~(size_t)255; return p; };
    u16* h0      = (u16*)alloc((size_t)NN * DH * 2);   // h0pre; reused as gh
    u16* hA      = (u16*)alloc((size_t)NN * DH * 2);
    int* csr     = (int*)alloc((size_t)NE * 4);
    int* cnt     = (int*)alloc((size_t)NN * 4);
    int* cursor  = (int*)alloc((size_t)NN * 4);
    int* rowptr  = (int*)alloc((size_t)(NN + 1) * 4);
    float* dinv  = (float*)alloc((size_t)NN * 4);
    u16* w12f    = (u16*)alloc(65536);
    u16* wgf     = (u16*)alloc(65536);
    u16* gh      = h0;  // alias: h0pre dead after aggregation

    hipMemsetAsync(cnt, 0, (size_t)NN * 4, stream);
    k_prep_hist<<<32 + NE / 256, 256, 0, stream>>>(w1, w2, wg, w12f, wgf, ei + NE, cnt);
    k_scan<<<1, 1024, 0, stream>>>(cnt, rowptr, cursor, dinv);
    k_fill<<<NE / 256, 256, 0, stream>>>(ei, ei + NE, cursor, csr);
    k_gemm_x<<<(NN + 127) / 128, 256, 0, stream>>>(x, wgf, dinv, h0);
    k_aggregate<<<NN / 4, 256, 0, stream>>>(h0, dinv, rowptr, csr, bg, hA);
    k_node_mlp<<<(NN + 127) / 128, 256, 0, stream>>>(hA, w12f, b1, b2, gh);
    k_edge_mlp<<<NE / 256, 256, 0, stream>>>(gh, ei, w12f, b2, ow, ob, out);
}